// Round 1
// baseline (229.298 us; speedup 1.0000x reference)
//
#include <hip/hip_runtime.h>
#include <stdint.h>

// ---------------------------------------------------------------------------
// CausalSelfAttention (B=2, T=2048, D=1024, H=16, Dh=64), fp32 in/out.
// Pipeline: cvt(fp32->bf16) -> QKV gemm (bf16 MFMA) -> flash attn -> out gemm.
// ---------------------------------------------------------------------------

typedef unsigned short u16;
typedef __attribute__((ext_vector_type(8))) __bf16 bf16x8;   // 4 VGPR MFMA A/B frag
typedef __attribute__((ext_vector_type(4))) float  f32x4;    // MFMA C/D frag
typedef __attribute__((ext_vector_type(4))) float  float4v;
typedef __attribute__((ext_vector_type(4))) unsigned short u16x4;
typedef __attribute__((ext_vector_type(8))) short  short8;   // raw 16B load

#define BB 2
#define TT 2048
#define DD 1024
#define HH 16
#define DH 64
#define MM (BB*TT)          // 4096 rows

static __device__ __forceinline__ u16 f2bf(float f) {
    uint32_t u = __builtin_bit_cast(uint32_t, f);
    u += 0x7FFFu + ((u >> 16) & 1u);          // round-to-nearest-even
    return (u16)(u >> 16);
}

// global(16B per lane) -> LDS direct copy. dst_base must be wave-uniform;
// HW writes dst_base + lane*16.
static __device__ __forceinline__ void load_lds16(const u16* g, const u16* lds_base) {
    __builtin_amdgcn_global_load_lds(
        (const __attribute__((address_space(1))) void*)(uintptr_t)g,
        (__attribute__((address_space(3)))  void*)(uint32_t)(uintptr_t)lds_base,
        16u, 0, 0u);
}

static __device__ __forceinline__ f32x4 mfma_bf16(bf16x8 a, bf16x8 b, f32x4 c) {
    return __builtin_amdgcn_mfma_f32_16x16x32_bf16(a, b, c, 0, 0, 0);
}

// ------------------------------ fp32 -> bf16 -------------------------------
__global__ __launch_bounds__(256) void cvt_kernel(const float* __restrict__ src,
                                                  u16* __restrict__ dst, int n4) {
    int i = blockIdx.x * blockDim.x + threadIdx.x;
    int stride = gridDim.x * blockDim.x;
    for (; i < n4; i += stride) {
        float4v v = ((const float4v*)src)[i];
        u16x4 o;
        o[0] = f2bf(v[0]); o[1] = f2bf(v[1]); o[2] = f2bf(v[2]); o[3] = f2bf(v[3]);
        ((u16x4*)dst)[i] = o;
    }
}

// ------------------------- GEMM  C = A * W^T + bias ------------------------
// A: [M,K] bf16 row-major. W: [z][N,K] bf16 row-major (z = blockIdx.z).
// OUTF32==0: bf16 out at outb + z*M*N ; OUTF32==1: f32 out to outf.
// 128x128 tile, BK=32, 256 threads (4 waves, 2x2 of 64x64), m97 structure.
template<int OUTF32>
__global__ __launch_bounds__(256) void gemm_nt(const u16* __restrict__ A,
        const u16* __restrict__ W,
        const float* __restrict__ b0, const float* __restrict__ b1,
        const float* __restrict__ b2,
        u16* __restrict__ outb, float* __restrict__ outf,
        int M, int N, int K) {
    __shared__ alignas(16) u16 As[128 * 32];
    __shared__ alignas(16) u16 Bs[128 * 32];

    const int tid  = threadIdx.x;
    const int wave = tid >> 6, lane = tid & 63;
    const int lr = lane & 15, lg = lane >> 4;
    const int wr = wave >> 1, wc = wave & 1;
    const int z  = blockIdx.z;
    const int m0 = blockIdx.x * 128;
    const int n0 = blockIdx.y * 128;

    const u16* Wz = W + (size_t)z * N * K;
    const float* bias = (z == 0) ? b0 : (z == 1) ? b1 : b2;

    f32x4 acc[4][4];
#pragma unroll
    for (int m = 0; m < 4; ++m)
#pragma unroll
        for (int n = 0; n < 4; ++n) acc[m][n] = (f32x4){0.f, 0.f, 0.f, 0.f};

    for (int k0 = 0; k0 < K; k0 += 32) {
        __syncthreads();
        // stage A and B tiles: 512 chunks of 16B each, 2 per thread per matrix
#pragma unroll
        for (int it = 0; it < 2; ++it) {
            int c = it * 256 + tid;
            int row = c >> 2, cc = (c & 3) * 8;
            const u16* gA = A  + (size_t)(m0 + row) * K + k0 + cc;
            const u16* gB = Wz + (size_t)(n0 + row) * K + k0 + cc;
            load_lds16(gA, As + (size_t)(it * 256 + wave * 64) * 8);
            load_lds16(gB, Bs + (size_t)(it * 256 + wave * 64) * 8);
        }
        __syncthreads();

        bf16x8 af[4], bfm[4];
#pragma unroll
        for (int m = 0; m < 4; ++m)
            af[m] = *(const bf16x8*)&As[(wr * 64 + m * 16 + lr) * 32 + lg * 8];
#pragma unroll
        for (int n = 0; n < 4; ++n)
            bfm[n] = *(const bf16x8*)&Bs[(wc * 64 + n * 16 + lr) * 32 + lg * 8];
#pragma unroll
        for (int m = 0; m < 4; ++m)
#pragma unroll
            for (int n = 0; n < 4; ++n)
                acc[m][n] = mfma_bf16(af[m], bfm[n], acc[m][n]);
    }

    // epilogue: C/D layout col = lane&15, row = (lane>>4)*4 + reg
#pragma unroll
    for (int n = 0; n < 4; ++n) {
        int col = n0 + wc * 64 + n * 16 + lr;
        float bv = bias[col];
#pragma unroll
        for (int m = 0; m < 4; ++m) {
            int row = m0 + wr * 64 + m * 16 + lg * 4;
#pragma unroll
            for (int r = 0; r < 4; ++r) {
                float v = acc[m][n][r] + bv;
                if (OUTF32 == 0)
                    outb[(size_t)z * M * N + (size_t)(row + r) * N + col] = f2bf(v);
                else
                    outf[(size_t)(row + r) * N + col] = v;
            }
        }
    }
}

// ------------------------------- attention ---------------------------------
// grid (T/64, B*H), 256 threads. Wave w owns q rows [qb*64+w*16, +16).
// KV tiles of 64. Q/K/V stored [B*T, D] bf16; head h = cols h*64..h*64+63.
__global__ __launch_bounds__(256) void attn_kernel(const u16* __restrict__ Qb,
        const u16* __restrict__ Kb, const u16* __restrict__ Vb,
        u16* __restrict__ Yb) {
    __shared__ alignas(16) u16 Ks[64 * 64];     // [key][d], XOR-swizzled 16B slots
    __shared__ alignas(16) u16 Vt[64 * 72];     // [d][key], stride 72
    __shared__ alignas(16) u16 Pl[4 * 16 * 64]; // per-wave P scratch, swizzled

    const int tid  = threadIdx.x;
    const int wave = tid >> 6, lane = tid & 63;
    const int lr = lane & 15, lg = lane >> 4;
    const int qb = blockIdx.x;
    const int bh = blockIdx.y;
    const int b = bh >> 4, h = bh & 15;
    const size_t rb = (size_t)b * TT;
    const int hoff = h * DH;
    const int q0 = qb * 64 + wave * 16;

    // Q fragments (A-operand): row = lane&15, k = (lane>>4)*8 + j (+32 for kk=1)
    bf16x8 qf[2];
    {
        const u16* qrow = Qb + (rb + q0 + lr) * DD + hoff + lg * 8;
        qf[0] = *(const bf16x8*)qrow;
        qf[1] = *(const bf16x8*)(qrow + 32);
    }

    float m_i[4] = {-1e30f, -1e30f, -1e30f, -1e30f};
    float l_i[4] = {0.f, 0.f, 0.f, 0.f};
    f32x4 o[4];
#pragma unroll
    for (int dn = 0; dn < 4; ++dn) o[dn] = (f32x4){0.f, 0.f, 0.f, 0.f};

    u16* Pw = Pl + wave * (16 * 64);

    for (int kt = 0; kt <= qb; ++kt) {
        const int kv0 = kt * 64;
        __syncthreads();
        // K tile: global_load_lds, source pre-swizzled so swizzled reads see K[key][d]
#pragma unroll
        for (int it = 0; it < 2; ++it) {
            int c = it * 256 + tid;
            int row = c >> 3;
            int gslot = (c & 7) ^ (row & 7);
            const u16* g = Kb + (rb + kv0 + row) * DD + hoff + gslot * 8;
            load_lds16(g, Ks + (size_t)(it * 256 + wave * 64) * 8);
        }
        // V tile transposed: Vt[d][key], key = c&63 keeps ds writes conflict-free
#pragma unroll
        for (int it = 0; it < 2; ++it) {
            int c = it * 256 + tid;
            int key = c & 63;
            int d0 = (c >> 6) * 8;
            short8 v = *(const short8*)(Vb + (rb + kv0 + key) * DD + hoff + d0);
#pragma unroll
            for (int j = 0; j < 8; ++j) Vt[(d0 + j) * 72 + key] = (u16)v[j];
        }
        __syncthreads();

        // S = Q K^T : s[kn] covers keys kn*16 + (lane&15)
        f32x4 s[4];
#pragma unroll
        for (int kn = 0; kn < 4; ++kn) {
            s[kn] = (f32x4){0.f, 0.f, 0.f, 0.f};
            int row = kn * 16 + lr;
#pragma unroll
            for (int kk = 0; kk < 2; ++kk) {
                int off = ((kk * 32 + lg * 8) * 2) ^ ((row & 7) << 4);
                bf16x8 kf = *(const bf16x8*)((const char*)Ks + row * 128 + off);
                s[kn] = mfma_bf16(qf[kk], kf, s[kn]);
            }
        }

        float sv[4][4];
        const bool lastt = (kt == qb);
#pragma unroll
        for (int kn = 0; kn < 4; ++kn)
#pragma unroll
            for (int r = 0; r < 4; ++r) {
                float v = s[kn][r] * 0.125f;
                if (lastt && (kv0 + kn * 16 + lr > q0 + lg * 4 + r)) v = -1e30f;
                sv[kn][r] = v;
            }

        // online softmax; row r lives in the 16 lanes sharing lg
#pragma unroll
        for (int r = 0; r < 4; ++r) {
            float mx = fmaxf(fmaxf(sv[0][r], sv[1][r]), fmaxf(sv[2][r], sv[3][r]));
            mx = fmaxf(mx, __shfl_xor(mx, 1));
            mx = fmaxf(mx, __shfl_xor(mx, 2));
            mx = fmaxf(mx, __shfl_xor(mx, 4));
            mx = fmaxf(mx, __shfl_xor(mx, 8));
            float mnew  = fmaxf(m_i[r], mx);
            float alpha = __expf(m_i[r] - mnew);
            float rs = 0.f;
#pragma unroll
            for (int kn = 0; kn < 4; ++kn) {
                float p = __expf(sv[kn][r] - mnew);
                sv[kn][r] = p;
                rs += p;
            }
            rs += __shfl_xor(rs, 1);
            rs += __shfl_xor(rs, 2);
            rs += __shfl_xor(rs, 4);
            rs += __shfl_xor(rs, 8);
            l_i[r] = l_i[r] * alpha + rs;
            m_i[r] = mnew;
#pragma unroll
            for (int dn = 0; dn < 4; ++dn) o[dn][r] *= alpha;
        }

        // P: C-layout -> LDS (swizzled) -> A-layout frags (per-wave region)
#pragma unroll
        for (int r = 0; r < 4; ++r) {
            int row = lg * 4 + r;
#pragma unroll
            for (int kn = 0; kn < 4; ++kn) {
                int off = ((kn * 16 + lr) * 2) ^ ((row & 7) << 4);
                *(u16*)((char*)Pw + row * 128 + off) = f2bf(sv[kn][r]);
            }
        }
        asm volatile("s_waitcnt lgkmcnt(0)" ::: "memory");
        bf16x8 pa[2];
#pragma unroll
        for (int kk = 0; kk < 2; ++kk) {
            int off = ((kk * 32 + lg * 8) * 2) ^ ((lr & 7) << 4);
            pa[kk] = *(const bf16x8*)((const char*)Pw + lr * 128 + off);
        }

        // O += P * V   (B-operand from transposed Vt: contiguous in k)
#pragma unroll
        for (int dn = 0; dn < 4; ++dn)
#pragma unroll
            for (int kk = 0; kk < 2; ++kk) {
                bf16x8 vf = *(const bf16x8*)&Vt[(dn * 16 + lr) * 72 + kk * 32 + lg * 8];
                o[dn] = mfma_bf16(pa[kk], vf, o[dn]);
            }
    }

#pragma unroll
    for (int r = 0; r < 4; ++r) {
        float inv = 1.0f / l_i[r];
        u16* yrow = Yb + (rb + q0 + lg * 4 + r) * DD + hoff;
#pragma unroll
        for (int dn = 0; dn < 4; ++dn) yrow[dn * 16 + lr] = f2bf(o[dn][r] * inv);
    }
}

// ------------------------------- launcher ----------------------------------
extern "C" void kernel_launch(void* const* d_in, const int* in_sizes, int n_in,
                              void* d_out, int out_size, void* d_ws, size_t ws_size,
                              hipStream_t stream) {
    const float* x  = (const float*)d_in[0];
    const float* Wq = (const float*)d_in[1];
    const float* bq = (const float*)d_in[2];
    const float* Wk = (const float*)d_in[3];
    const float* bk = (const float*)d_in[4];
    const float* Wv = (const float*)d_in[5];
    const float* bv = (const float*)d_in[6];
    const float* Wo = (const float*)d_in[7];
    const float* bo = (const float*)d_in[8];
    float* out = (float*)d_out;

    const size_t XN = (size_t)MM * DD;   // 4,194,304
    const size_t WN = (size_t)DD * DD;   // 1,048,576

    u16* xb  = (u16*)d_ws;
    u16* Wb  = xb  + XN;          // Wq,Wk,Wv stacked: 3*WN
    u16* Wob = Wb  + 3 * WN;
    u16* QKV = Wob + WN;          // Q,K,V stacked: 3*XN
    u16* Yb  = QKV + 3 * XN;

    cvt_kernel<<<4096, 256, 0, stream>>>(x,  xb,           (int)(XN / 4));
    cvt_kernel<<<1024, 256, 0, stream>>>(Wq, Wb,           (int)(WN / 4));
    cvt_kernel<<<1024, 256, 0, stream>>>(Wk, Wb + WN,      (int)(WN / 4));
    cvt_kernel<<<1024, 256, 0, stream>>>(Wv, Wb + 2 * WN,  (int)(WN / 4));
    cvt_kernel<<<1024, 256, 0, stream>>>(Wo, Wob,          (int)(WN / 4));

    gemm_nt<0><<<dim3(32, 8, 3), 256, 0, stream>>>(xb, Wb, bq, bk, bv,
                                                   QKV, nullptr, MM, DD, DD);
    attn_kernel<<<dim3(TT / 64, BB * HH), 256, 0, stream>>>(QKV, QKV + XN,
                                                            QKV + 2 * XN, Yb);
    gemm_nt<1><<<dim3(32, 8, 1), 256, 0, stream>>>(Yb, Wob, bo, bo, bo,
                                                   nullptr, out, MM, DD, DD);
}

// Round 2
// 147.465 us; speedup vs baseline: 1.5549x; 1.5549x over previous
//
#include <hip/hip_runtime.h>
#include <stdint.h>

// ---------------------------------------------------------------------------
// CausalSelfAttention (B=2, T=2048, D=1024, H=16, Dh=64), fp32 in/out.
// cvt(fp32->bf16) -> QKV gemm (bf16 MFMA) -> flash attn (32x32 swapped) -> out gemm.
// ---------------------------------------------------------------------------

typedef unsigned short u16;
typedef __attribute__((ext_vector_type(8)))  __bf16 bf16x8;   // 4 VGPR MFMA A/B frag
typedef __attribute__((ext_vector_type(4)))  float  f32x4;    // 16x16 C/D frag
typedef __attribute__((ext_vector_type(16))) float  f32x16;   // 32x32 C/D frag
typedef __attribute__((ext_vector_type(4)))  float  float4v;
typedef __attribute__((ext_vector_type(4)))  unsigned short u16x4;
typedef __attribute__((ext_vector_type(4)))  unsigned int   u32x4;
typedef __attribute__((ext_vector_type(8)))  short  short8;   // raw 16B load

#define BB 2
#define TT 2048
#define DD 1024
#define HH 16
#define DH 64
#define MM (BB*TT)          // 4096 rows

static __device__ __forceinline__ u16 f2bf(float f) {
    uint32_t u = __builtin_bit_cast(uint32_t, f);
    u += 0x7FFFu + ((u >> 16) & 1u);          // round-to-nearest-even
    return (u16)(u >> 16);
}

// pack two f32 -> one u32 of two bf16 (low = a, high = b)
static __device__ __forceinline__ unsigned cvt_pk_bf16(float a, float b) {
    unsigned r;
    asm("v_cvt_pk_bf16_f32 %0, %1, %2" : "=v"(r) : "v"(a), "v"(b));
    return r;
}

// global(16B per lane) -> LDS direct copy. dst_base must be wave-uniform;
// HW writes dst_base + lane*16.
static __device__ __forceinline__ void load_lds16(const u16* g, const u16* lds_base) {
    __builtin_amdgcn_global_load_lds(
        (const __attribute__((address_space(1))) void*)(uintptr_t)g,
        (__attribute__((address_space(3)))  void*)(uint32_t)(uintptr_t)lds_base,
        16u, 0, 0u);
}

static __device__ __forceinline__ f32x4 mfma16(bf16x8 a, bf16x8 b, f32x4 c) {
    return __builtin_amdgcn_mfma_f32_16x16x32_bf16(a, b, c, 0, 0, 0);
}
static __device__ __forceinline__ f32x16 mfma32(bf16x8 a, bf16x8 b, f32x16 c) {
    return __builtin_amdgcn_mfma_f32_32x32x16_bf16(a, b, c, 0, 0, 0);
}

// ------------------------------ fp32 -> bf16 -------------------------------
__global__ __launch_bounds__(256) void cvt_kernel(const float* __restrict__ src,
                                                  u16* __restrict__ dst, int n4) {
    int i = blockIdx.x * blockDim.x + threadIdx.x;
    int stride = gridDim.x * blockDim.x;
    for (; i < n4; i += stride) {
        float4v v = ((const float4v*)src)[i];
        u16x4 o;
        o[0] = f2bf(v[0]); o[1] = f2bf(v[1]); o[2] = f2bf(v[2]); o[3] = f2bf(v[3]);
        ((u16x4*)dst)[i] = o;
    }
}

// ------------------------- GEMM  C = A * W^T + bias ------------------------
// A: [M,K] bf16 row-major. W: [z][N,K] bf16 row-major (z = blockIdx.z).
// OUTF32==0: bf16 out at outb + z*M*N ; OUTF32==1: f32 out to outf.
// 128x128 tile, BK=32, 256 threads (4 waves, 2x2 of 64x64), m97 structure.
template<int OUTF32>
__global__ __launch_bounds__(256) void gemm_nt(const u16* __restrict__ A,
        const u16* __restrict__ W,
        const float* __restrict__ b0, const float* __restrict__ b1,
        const float* __restrict__ b2,
        u16* __restrict__ outb, float* __restrict__ outf,
        int M, int N, int K) {
    __shared__ alignas(16) u16 As[128 * 32];
    __shared__ alignas(16) u16 Bs[128 * 32];

    const int tid  = threadIdx.x;
    const int wave = tid >> 6, lane = tid & 63;
    const int lr = lane & 15, lg = lane >> 4;
    const int wr = wave >> 1, wc = wave & 1;
    const int z  = blockIdx.z;
    const int m0 = blockIdx.x * 128;
    const int n0 = blockIdx.y * 128;

    const u16* Wz = W + (size_t)z * N * K;
    const float* bias = (z == 0) ? b0 : (z == 1) ? b1 : b2;

    f32x4 acc[4][4];
#pragma unroll
    for (int m = 0; m < 4; ++m)
#pragma unroll
        for (int n = 0; n < 4; ++n) acc[m][n] = (f32x4){0.f, 0.f, 0.f, 0.f};

    for (int k0 = 0; k0 < K; k0 += 32) {
        __syncthreads();
#pragma unroll
        for (int it = 0; it < 2; ++it) {
            int c = it * 256 + tid;
            int row = c >> 2, cc = (c & 3) * 8;
            const u16* gA = A  + (size_t)(m0 + row) * K + k0 + cc;
            const u16* gB = Wz + (size_t)(n0 + row) * K + k0 + cc;
            load_lds16(gA, As + (size_t)(it * 256 + wave * 64) * 8);
            load_lds16(gB, Bs + (size_t)(it * 256 + wave * 64) * 8);
        }
        __syncthreads();

        bf16x8 af[4], bfm[4];
#pragma unroll
        for (int m = 0; m < 4; ++m)
            af[m] = *(const bf16x8*)&As[(wr * 64 + m * 16 + lr) * 32 + lg * 8];
#pragma unroll
        for (int n = 0; n < 4; ++n)
            bfm[n] = *(const bf16x8*)&Bs[(wc * 64 + n * 16 + lr) * 32 + lg * 8];
#pragma unroll
        for (int m = 0; m < 4; ++m)
#pragma unroll
            for (int n = 0; n < 4; ++n)
                acc[m][n] = mfma16(af[m], bfm[n], acc[m][n]);
    }

#pragma unroll
    for (int n = 0; n < 4; ++n) {
        int col = n0 + wc * 64 + n * 16 + lr;
        float bv = bias[col];
#pragma unroll
        for (int m = 0; m < 4; ++m) {
            int row = m0 + wr * 64 + m * 16 + lg * 4;
#pragma unroll
            for (int r = 0; r < 4; ++r) {
                float v = acc[m][n][r] + bv;
                if (OUTF32 == 0)
                    outb[(size_t)z * M * N + (size_t)(row + r) * N + col] = f2bf(v);
                else
                    outf[(size_t)(row + r) * N + col] = v;
            }
        }
    }
}

// ------------------------------- attention ---------------------------------
// grid (16, 32): qb = 15 - blockIdx.x (128 q rows per block, longest first),
// bh = blockIdx.y. 4 warps; warp w owns q rows [qb*128 + w*32, +32).
// Swapped-operand 32x32 MFMA: S^T = K·Q^T so each lane owns ONE q column
// (q = q0w + (lane&31)) and 16 of 32 keys -> in-register online softmax.
// PV: O^T = V^T·P^T keeps the same lane-owns-q layout (rescale = scalar mul).
__global__ __launch_bounds__(256) void attn_kernel(const u16* __restrict__ Qb,
        const u16* __restrict__ Kb, const u16* __restrict__ Vb,
        u16* __restrict__ Yb) {
    __shared__ alignas(16) u16 Ks[64 * 64];   // [key][d], XOR-swizzled 16B slots
    __shared__ alignas(16) u16 Vt[64 * 72];   // [d][key], stride 72 (16B aligned)

    const int tid  = threadIdx.x;
    const int wave = tid >> 6, lane = tid & 63;
    const int lq = lane & 31, hi = lane >> 5;
    const int qb = 15 - blockIdx.x;           // longest blocks dispatch first
    const int bh = blockIdx.y;
    const int b = bh >> 4, h = bh & 15;
    const size_t rb = (size_t)b * TT;
    const int hoff = h * DH;
    const int q0w = qb * 128 + wave * 32;     // warp q base (within this b)

    // Q fragments (B-operand): col=lane&31=q, k=(lane>>5)*8+j ; 4 chunks of 16
    bf16x8 qf[4];
    {
        const u16* qrow = Qb + (rb + q0w + lq) * DD + hoff + hi * 8;
#pragma unroll
        for (int kc = 0; kc < 4; ++kc) qf[kc] = *(const bf16x8*)(qrow + kc * 16);
    }

    f32x16 o0 = {}, o1 = {};
    float m_i = -1e30f, l_i = 0.f;
    const float cexp = 0.18033688011f;        // 0.125 * log2(e)

    const int nt = 2 * qb + 2;
    for (int kt = 0; kt < nt; ++kt) {
        const int kv0 = kt * 64;
        __syncthreads();
        // stage K: 512x16B chunks; LDS linear, source pre-swizzled (rule 21)
#pragma unroll
        for (int it = 0; it < 2; ++it) {
            int c = it * 256 + tid;
            int row = c >> 3, s = c & 7;
            const u16* g = Kb + (rb + kv0 + row) * DD + hoff + (s ^ (row & 7)) * 8;
            load_lds16(g, Ks + (size_t)(it * 256 + wave * 64) * 8);
        }
        // stage V transposed: Vt[d][key]
#pragma unroll
        for (int it = 0; it < 2; ++it) {
            int c = it * 256 + tid;
            int key = c & 63;
            int d0 = (c >> 6) * 8;
            short8 v = *(const short8*)(Vb + (rb + kv0 + key) * DD + hoff + d0);
#pragma unroll
            for (int j = 0; j < 8; ++j) Vt[(d0 + j) * 72 + key] = (u16)v[j];
        }
        __syncthreads();

        if (kv0 >= q0w + 32) continue;        // fully masked for this warp

        // S^T[key][q] = K · Q^T : A=K (row=key), B=Q (col=q)
        f32x16 st[2];
#pragma unroll
        for (int kb = 0; kb < 2; ++kb) {
            st[kb] = (f32x16){};
            const int rowm = ((32 * kb + lq) & 7);  // == lq&7
#pragma unroll
            for (int kc = 0; kc < 4; ++kc) {
                bf16x8 kf = *(const bf16x8*)&Ks[(32 * kb + lq) * 64 +
                                                ((2 * kc + hi) ^ rowm) * 8];
                st[kb] = mfma32(kf, qf[kc], st[kb]);
            }
        }

        // causal mask on raw scores (scale folded into exp2 constant)
        if (kv0 + 63 > q0w) {
            const int qrel = q0w + lq - kv0;
#pragma unroll
            for (int kb = 0; kb < 2; ++kb)
#pragma unroll
                for (int r = 0; r < 16; ++r) {
                    int key = 32 * kb + (r & 3) + 8 * (r >> 2) + 4 * hi;
                    if (key > qrel) st[kb][r] = -1e30f;
                }
        }

        // online softmax, fully in-lane (row = this lane's q)
        float pm = st[0][0];
#pragma unroll
        for (int r = 1; r < 16; ++r) pm = fmaxf(pm, st[0][r]);
#pragma unroll
        for (int r = 0; r < 16; ++r) pm = fmaxf(pm, st[1][r]);
        pm = fmaxf(pm, __shfl_xor(pm, 32));
        const float mnew  = fmaxf(m_i, pm);
        const float alpha = __builtin_amdgcn_exp2f((m_i - mnew) * cexp);
        float rs = 0.f;
#pragma unroll
        for (int kb = 0; kb < 2; ++kb)
#pragma unroll
            for (int r = 0; r < 16; ++r) {
                float p = __builtin_amdgcn_exp2f((st[kb][r] - mnew) * cexp);
                st[kb][r] = p;
                rs += p;
            }
        rs += __shfl_xor(rs, 32);
        l_i = l_i * alpha + rs;
        m_i = mnew;
#pragma unroll
        for (int r = 0; r < 16; ++r) { o0[r] *= alpha; o1[r] *= alpha; }

        // P^T -> B-operand frags: cvt_pk pairs + permlane32_swap (T12)
        bf16x8 pb[4];
#pragma unroll
        for (int ks = 0; ks < 4; ++ks) {
            const int kb = ks >> 1, base = 8 * (ks & 1);
            unsigned c0 = cvt_pk_bf16(st[kb][base + 0], st[kb][base + 1]);
            unsigned c1 = cvt_pk_bf16(st[kb][base + 2], st[kb][base + 3]);
            unsigned c2 = cvt_pk_bf16(st[kb][base + 4], st[kb][base + 5]);
            unsigned c3 = cvt_pk_bf16(st[kb][base + 6], st[kb][base + 7]);
            asm volatile("v_permlane32_swap_b32 %0, %1" : "+v"(c0), "+v"(c2));
            asm volatile("v_permlane32_swap_b32 %0, %1" : "+v"(c1), "+v"(c3));
            u32x4 w; w[0] = c0; w[1] = c1; w[2] = c2; w[3] = c3;
            pb[ks] = __builtin_bit_cast(bf16x8, w);
        }

        // O^T += V^T · P^T : A=V^T (row=d), B=P^T (col=q)
#pragma unroll
        for (int ks = 0; ks < 4; ++ks) {
            bf16x8 vf0 = *(const bf16x8*)&Vt[(lq)      * 72 + ks * 16 + hi * 8];
            bf16x8 vf1 = *(const bf16x8*)&Vt[(32 + lq) * 72 + ks * 16 + hi * 8];
            o0 = mfma32(vf0, pb[ks], o0);
            o1 = mfma32(vf1, pb[ks], o1);
        }
    }

    // epilogue: O^T C-layout col=q (=lane&31), row=d=(r&3)+8*(r>>2)+4*hi (+32 for o1)
    const float inv = 1.0f / l_i;
    u16* yrow = Yb + (rb + q0w + lq) * DD + hoff;
#pragma unroll
    for (int g = 0; g < 4; ++g) {
        u16x4 p0, p1;
#pragma unroll
        for (int j = 0; j < 4; ++j) {
            p0[j] = f2bf(o0[4 * g + j] * inv);
            p1[j] = f2bf(o1[4 * g + j] * inv);
        }
        *(u16x4*)&yrow[8 * g + 4 * hi]      = p0;
        *(u16x4*)&yrow[32 + 8 * g + 4 * hi] = p1;
    }
}

// ------------------------------- launcher ----------------------------------
extern "C" void kernel_launch(void* const* d_in, const int* in_sizes, int n_in,
                              void* d_out, int out_size, void* d_ws, size_t ws_size,
                              hipStream_t stream) {
    const float* x  = (const float*)d_in[0];
    const float* Wq = (const float*)d_in[1];
    const float* bq = (const float*)d_in[2];
    const float* Wk = (const float*)d_in[3];
    const float* bk = (const float*)d_in[4];
    const float* Wv = (const float*)d_in[5];
    const float* bv = (const float*)d_in[6];
    const float* Wo = (const float*)d_in[7];
    const float* bo = (const float*)d_in[8];
    float* out = (float*)d_out;

    const size_t XN = (size_t)MM * DD;   // 4,194,304
    const size_t WN = (size_t)DD * DD;   // 1,048,576

    u16* xb  = (u16*)d_ws;
    u16* Wb  = xb  + XN;          // Wq,Wk,Wv stacked: 3*WN
    u16* Wob = Wb  + 3 * WN;
    u16* QKV = Wob + WN;          // Q,K,V stacked: 3*XN
    u16* Yb  = QKV + 3 * XN;

    cvt_kernel<<<4096, 256, 0, stream>>>(x,  xb,           (int)(XN / 4));
    cvt_kernel<<<1024, 256, 0, stream>>>(Wq, Wb,           (int)(WN / 4));
    cvt_kernel<<<1024, 256, 0, stream>>>(Wk, Wb + WN,      (int)(WN / 4));
    cvt_kernel<<<1024, 256, 0, stream>>>(Wv, Wb + 2 * WN,  (int)(WN / 4));
    cvt_kernel<<<1024, 256, 0, stream>>>(Wo, Wob,          (int)(WN / 4));

    gemm_nt<0><<<dim3(32, 8, 3), 256, 0, stream>>>(xb, Wb, bq, bk, bv,
                                                   QKV, nullptr, MM, DD, DD);
    attn_kernel<<<dim3(16, BB * HH), 256, 0, stream>>>(QKV, QKV + XN,
                                                       QKV + 2 * XN, Yb);
    gemm_nt<1><<<dim3(32, 8, 1), 256, 0, stream>>>(Yb, Wob, bo, bo, bo,
                                                   nullptr, out, MM, DD, DD);
}

// Round 3
// 143.292 us; speedup vs baseline: 1.6002x; 1.0291x over previous
//
#include <hip/hip_runtime.h>
#include <stdint.h>

// ---------------------------------------------------------------------------
// CausalSelfAttention (B=2, T=2048, D=1024, H=16, Dh=64), fp32 in/out.
// cvt(fp32->bf16) -> QKV gemm (bf16 MFMA) -> flash attn (32x32 swapped,
// double-buffered KV pipeline) -> out gemm.
// ---------------------------------------------------------------------------

typedef unsigned short u16;
typedef __attribute__((ext_vector_type(8)))  __bf16 bf16x8;   // 4 VGPR MFMA A/B frag
typedef __attribute__((ext_vector_type(4)))  float  f32x4;    // 16x16 C/D frag
typedef __attribute__((ext_vector_type(16))) float  f32x16;   // 32x32 C/D frag
typedef __attribute__((ext_vector_type(4)))  float  float4v;
typedef __attribute__((ext_vector_type(4)))  unsigned short u16x4;
typedef __attribute__((ext_vector_type(4)))  unsigned int   u32x4;
typedef __attribute__((ext_vector_type(8)))  short  short8;   // raw 16B load

#define BB 2
#define TT 2048
#define DD 1024
#define HH 16
#define DH 64
#define MM (BB*TT)          // 4096 rows

static __device__ __forceinline__ u16 f2bf(float f) {
    uint32_t u = __builtin_bit_cast(uint32_t, f);
    u += 0x7FFFu + ((u >> 16) & 1u);          // round-to-nearest-even
    return (u16)(u >> 16);
}

// pack two f32 -> one u32 of two bf16 (low = a, high = b)
static __device__ __forceinline__ unsigned cvt_pk_bf16(float a, float b) {
    unsigned r;
    asm("v_cvt_pk_bf16_f32 %0, %1, %2" : "=v"(r) : "v"(a), "v"(b));
    return r;
}

// global(16B per lane) -> LDS direct copy. dst_base must be wave-uniform;
// HW writes dst_base + lane*16.
static __device__ __forceinline__ void load_lds16(const u16* g, const u16* lds_base) {
    __builtin_amdgcn_global_load_lds(
        (const __attribute__((address_space(1))) void*)(uintptr_t)g,
        (__attribute__((address_space(3)))  void*)(uint32_t)(uintptr_t)lds_base,
        16u, 0, 0u);
}

static __device__ __forceinline__ f32x4 mfma16(bf16x8 a, bf16x8 b, f32x4 c) {
    return __builtin_amdgcn_mfma_f32_16x16x32_bf16(a, b, c, 0, 0, 0);
}
static __device__ __forceinline__ f32x16 mfma32(bf16x8 a, bf16x8 b, f32x16 c) {
    return __builtin_amdgcn_mfma_f32_32x32x16_bf16(a, b, c, 0, 0, 0);
}

// ------------------------------ fp32 -> bf16 -------------------------------
__global__ __launch_bounds__(256) void cvt_kernel(const float* __restrict__ src,
                                                  u16* __restrict__ dst, int n4) {
    int i = blockIdx.x * blockDim.x + threadIdx.x;
    int stride = gridDim.x * blockDim.x;
    for (; i < n4; i += stride) {
        float4v v = ((const float4v*)src)[i];
        u16x4 o;
        o[0] = f2bf(v[0]); o[1] = f2bf(v[1]); o[2] = f2bf(v[2]); o[3] = f2bf(v[3]);
        ((u16x4*)dst)[i] = o;
    }
}

// four matrices in one launch (z = blockIdx.y selects)
__global__ __launch_bounds__(256) void cvt4_kernel(const float* __restrict__ s0,
        const float* __restrict__ s1, const float* __restrict__ s2,
        const float* __restrict__ s3, u16* __restrict__ d0, u16* __restrict__ d1,
        u16* __restrict__ d2, u16* __restrict__ d3, int n4) {
    const int z = blockIdx.y;
    const float* src = (z == 0) ? s0 : (z == 1) ? s1 : (z == 2) ? s2 : s3;
    u16* dst = (z == 0) ? d0 : (z == 1) ? d1 : (z == 2) ? d2 : d3;
    int i = blockIdx.x * blockDim.x + threadIdx.x;
    int stride = gridDim.x * blockDim.x;
    for (; i < n4; i += stride) {
        float4v v = ((const float4v*)src)[i];
        u16x4 o;
        o[0] = f2bf(v[0]); o[1] = f2bf(v[1]); o[2] = f2bf(v[2]); o[3] = f2bf(v[3]);
        ((u16x4*)dst)[i] = o;
    }
}

// ------------------------- GEMM  C = A * W^T + bias ------------------------
// A: [M,K] bf16 row-major. W: [z][N,K] bf16 row-major (z = blockIdx.z).
// OUTF32==0: bf16 out at outb + z*M*N ; OUTF32==1: f32 out to outf.
// 128x128 tile, BK=32, 256 threads (4 waves, 2x2 of 64x64), m97 structure.
template<int OUTF32>
__global__ __launch_bounds__(256) void gemm_nt(const u16* __restrict__ A,
        const u16* __restrict__ W,
        const float* __restrict__ b0, const float* __restrict__ b1,
        const float* __restrict__ b2,
        u16* __restrict__ outb, float* __restrict__ outf,
        int M, int N, int K) {
    __shared__ alignas(16) u16 As[128 * 32];
    __shared__ alignas(16) u16 Bs[128 * 32];

    const int tid  = threadIdx.x;
    const int wave = tid >> 6, lane = tid & 63;
    const int lr = lane & 15, lg = lane >> 4;
    const int wr = wave >> 1, wc = wave & 1;
    const int z  = blockIdx.z;
    const int m0 = blockIdx.x * 128;
    const int n0 = blockIdx.y * 128;

    const u16* Wz = W + (size_t)z * N * K;
    const float* bias = (z == 0) ? b0 : (z == 1) ? b1 : b2;

    f32x4 acc[4][4];
#pragma unroll
    for (int m = 0; m < 4; ++m)
#pragma unroll
        for (int n = 0; n < 4; ++n) acc[m][n] = (f32x4){0.f, 0.f, 0.f, 0.f};

    for (int k0 = 0; k0 < K; k0 += 32) {
        __syncthreads();
#pragma unroll
        for (int it = 0; it < 2; ++it) {
            int c = it * 256 + tid;
            int row = c >> 2, cc = (c & 3) * 8;
            const u16* gA = A  + (size_t)(m0 + row) * K + k0 + cc;
            const u16* gB = Wz + (size_t)(n0 + row) * K + k0 + cc;
            load_lds16(gA, As + (size_t)(it * 256 + wave * 64) * 8);
            load_lds16(gB, Bs + (size_t)(it * 256 + wave * 64) * 8);
        }
        __syncthreads();

        bf16x8 af[4], bfm[4];
#pragma unroll
        for (int m = 0; m < 4; ++m)
            af[m] = *(const bf16x8*)&As[(wr * 64 + m * 16 + lr) * 32 + lg * 8];
#pragma unroll
        for (int n = 0; n < 4; ++n)
            bfm[n] = *(const bf16x8*)&Bs[(wc * 64 + n * 16 + lr) * 32 + lg * 8];
#pragma unroll
        for (int m = 0; m < 4; ++m)
#pragma unroll
            for (int n = 0; n < 4; ++n)
                acc[m][n] = mfma16(af[m], bfm[n], acc[m][n]);
    }

#pragma unroll
    for (int n = 0; n < 4; ++n) {
        int col = n0 + wc * 64 + n * 16 + lr;
        float bv = bias[col];
#pragma unroll
        for (int m = 0; m < 4; ++m) {
            int row = m0 + wr * 64 + m * 16 + lg * 4;
#pragma unroll
            for (int r = 0; r < 4; ++r) {
                float v = acc[m][n][r] + bv;
                if (OUTF32 == 0)
                    outb[(size_t)z * M * N + (size_t)(row + r) * N + col] = f2bf(v);
                else
                    outf[(size_t)(row + r) * N + col] = v;
            }
        }
    }
}

// ------------------------------- attention ---------------------------------
// grid (16, 32): qb = 15 - blockIdx.x (128 q rows per block), bh = blockIdx.y.
// 4 warps; warp w owns q rows [qb*128 + w*32, +32).
// Swapped-operand 32x32 MFMA: S^T = K·Q^T so each lane owns ONE q column
// (q = q0w + (lane&31)); softmax fully in-lane; O^T = V^T·P^T keeps layout.
// KV double-buffered: stage(t+1) issued before compute(t) (T3+T14); V's
// transposed ds_writes land after compute; one barrier per tile.
__global__ __launch_bounds__(256) void attn_kernel(const u16* __restrict__ Qb,
        const u16* __restrict__ Kb, const u16* __restrict__ Vb,
        u16* __restrict__ Yb) {
    __shared__ alignas(16) u16 Ks[2][64 * 64];   // [key][d], XOR-swizzled 16B slots
    __shared__ alignas(16) u16 Vt[2][64 * 72];   // [d][key], stride 72

    const int tid  = threadIdx.x;
    const int wave = tid >> 6, lane = tid & 63;
    const int lq = lane & 31, hi = lane >> 5;
    const int qb = 15 - blockIdx.x;              // longest blocks dispatch first
    const int bh = blockIdx.y;
    const int b = bh >> 4, h = bh & 15;
    const size_t rb = (size_t)b * TT;
    const int hoff = h * DH;
    const int q0w = qb * 128 + wave * 32;        // warp q base (within this b)

    // staging coordinates (uniform per thread across tiles)
    const int krow0 = tid >> 3, ks0 = tid & 7;           // K chunk, it=0
    const int krow1 = (256 + tid) >> 3, ks1 = tid & 7;   // K chunk, it=1
    const int vkey = tid & 63;                           // V row
    const int vd0a = (tid >> 6) * 8, vd0b = vd0a + 32;   // V d-ranges (it=0/1)

    const u16* Kbh = Kb + rb * DD + hoff;
    const u16* Vbh = Vb + rb * DD + hoff;

    // Q fragments (B-operand): col=lane&31=q, k=(lane>>5)*8+j ; 4 chunks of 16
    bf16x8 qf[4];
    {
        const u16* qrow = Qb + (rb + q0w + lq) * DD + hoff + hi * 8;
#pragma unroll
        for (int kc = 0; kc < 4; ++kc) qf[kc] = *(const bf16x8*)(qrow + kc * 16);
    }

    f32x16 o0 = {}, o1 = {};
    float m_i = -1e30f, l_i = 0.f;
    const float cexp = 0.18033688011f;        // 0.125 * log2(e)
    const int nt = 2 * qb + 2;

    short8 vreg0, vreg1;

    // ---- prologue: stage tile 0 into buffer 0
    load_lds16(Kbh + (size_t)krow0 * DD + (ks0 ^ (krow0 & 7)) * 8,
               &Ks[0][(size_t)(wave * 64) * 8]);
    load_lds16(Kbh + (size_t)krow1 * DD + (ks1 ^ (krow1 & 7)) * 8,
               &Ks[0][(size_t)(256 + wave * 64) * 8]);
    vreg0 = *(const short8*)(Vbh + (size_t)vkey * DD + vd0a);
    vreg1 = *(const short8*)(Vbh + (size_t)vkey * DD + vd0b);
#pragma unroll
    for (int j = 0; j < 8; ++j) {
        Vt[0][(vd0a + j) * 72 + vkey] = (u16)vreg0[j];
        Vt[0][(vd0b + j) * 72 + vkey] = (u16)vreg1[j];
    }
    __syncthreads();

    for (int kt = 0; kt < nt; ++kt) {
        const int cur = kt & 1, nxt = cur ^ 1;
        const int kv0 = kt * 64;
        const bool pre = (kt + 1 < nt);

        // ---- issue next-tile loads EARLY (latency hides under compute)
        if (pre) {
            const u16* Kt = Kbh + (size_t)(kv0 + 64) * DD;
            load_lds16(Kt + (size_t)krow0 * DD + (ks0 ^ (krow0 & 7)) * 8,
                       &Ks[nxt][(size_t)(wave * 64) * 8]);
            load_lds16(Kt + (size_t)krow1 * DD + (ks1 ^ (krow1 & 7)) * 8,
                       &Ks[nxt][(size_t)(256 + wave * 64) * 8]);
            const u16* Vrow = Vbh + (size_t)(kv0 + 64 + vkey) * DD;
            vreg0 = *(const short8*)(Vrow + vd0a);
            vreg1 = *(const short8*)(Vrow + vd0b);
        }

        if (kv0 < q0w + 32) {   // not fully masked for this warp
            // S^T[key][q] = K · Q^T : A=K (row=key), B=Q (col=q)
            f32x16 st[2];
#pragma unroll
            for (int kb = 0; kb < 2; ++kb) {
                st[kb] = (f32x16){};
                const int rowm = lq & 7;
#pragma unroll
                for (int kc = 0; kc < 4; ++kc) {
                    bf16x8 kf = *(const bf16x8*)&Ks[cur][(32 * kb + lq) * 64 +
                                                    ((2 * kc + hi) ^ rowm) * 8];
                    st[kb] = mfma32(kf, qf[kc], st[kb]);
                }
            }

            // causal mask on raw scores (scale folded into exp2 constant)
            if (kv0 + 63 > q0w) {
                const int qrel = q0w + lq - kv0;
#pragma unroll
                for (int kb = 0; kb < 2; ++kb)
#pragma unroll
                    for (int r = 0; r < 16; ++r) {
                        int key = 32 * kb + (r & 3) + 8 * (r >> 2) + 4 * hi;
                        if (key > qrel) st[kb][r] = -1e30f;
                    }
            }

            // online softmax, fully in-lane (row = this lane's q)
            float pm = st[0][0];
#pragma unroll
            for (int r = 1; r < 16; ++r) pm = fmaxf(pm, st[0][r]);
#pragma unroll
            for (int r = 0; r < 16; ++r) pm = fmaxf(pm, st[1][r]);
            pm = fmaxf(pm, __shfl_xor(pm, 32));
            // defer-max (T13): only rescale when the max grew past THR=8/cexp
            if (!__all(pm - m_i <= 44.3614f)) {
                const float mnew  = fmaxf(m_i, pm);
                const float alpha = __builtin_amdgcn_exp2f((m_i - mnew) * cexp);
                l_i *= alpha;
#pragma unroll
                for (int r = 0; r < 16; ++r) { o0[r] *= alpha; o1[r] *= alpha; }
                m_i = mnew;
            }
            float rs = 0.f;
#pragma unroll
            for (int kb = 0; kb < 2; ++kb)
#pragma unroll
                for (int r = 0; r < 16; ++r) {
                    float p = __builtin_amdgcn_exp2f((st[kb][r] - m_i) * cexp);
                    st[kb][r] = p;
                    rs += p;
                }
            rs += __shfl_xor(rs, 32);
            l_i += rs;

            // P^T -> B-operand frags: cvt_pk pairs + permlane32_swap (T12)
            bf16x8 pb[4];
#pragma unroll
            for (int ks = 0; ks < 4; ++ks) {
                const int kb = ks >> 1, base = 8 * (ks & 1);
                unsigned c0 = cvt_pk_bf16(st[kb][base + 0], st[kb][base + 1]);
                unsigned c1 = cvt_pk_bf16(st[kb][base + 2], st[kb][base + 3]);
                unsigned c2 = cvt_pk_bf16(st[kb][base + 4], st[kb][base + 5]);
                unsigned c3 = cvt_pk_bf16(st[kb][base + 6], st[kb][base + 7]);
                asm volatile("v_permlane32_swap_b32 %0, %1" : "+v"(c0), "+v"(c2));
                asm volatile("v_permlane32_swap_b32 %0, %1" : "+v"(c1), "+v"(c3));
                u32x4 w; w[0] = c0; w[1] = c1; w[2] = c2; w[3] = c3;
                pb[ks] = __builtin_bit_cast(bf16x8, w);
            }

            // O^T += V^T · P^T : A=V^T (row=d), B=P^T (col=q)
#pragma unroll
            for (int ks = 0; ks < 4; ++ks) {
                bf16x8 vf0 = *(const bf16x8*)&Vt[cur][(lq)      * 72 + ks * 16 + hi * 8];
                bf16x8 vf1 = *(const bf16x8*)&Vt[cur][(32 + lq) * 72 + ks * 16 + hi * 8];
                o0 = mfma32(vf0, pb[ks], o0);
                o1 = mfma32(vf1, pb[ks], o1);
            }
        }

        // ---- late half of V staging: regs -> LDS (waits vmcnt for vreg only)
        if (pre) {
#pragma unroll
            for (int j = 0; j < 8; ++j) {
                Vt[nxt][(vd0a + j) * 72 + vkey] = (u16)vreg0[j];
                Vt[nxt][(vd0b + j) * 72 + vkey] = (u16)vreg1[j];
            }
        }
        __syncthreads();   // drains vmcnt(0): next tile's K gload_lds complete
    }

    // epilogue: O^T C-layout col=q (=lane&31), row=d=(r&3)+8*(r>>2)+4*hi (+32 for o1)
    const float inv = 1.0f / l_i;
    u16* yrow = Yb + (rb + q0w + lq) * DD + hoff;
#pragma unroll
    for (int g = 0; g < 4; ++g) {
        u16x4 p0, p1;
#pragma unroll
        for (int j = 0; j < 4; ++j) {
            p0[j] = f2bf(o0[4 * g + j] * inv);
            p1[j] = f2bf(o1[4 * g + j] * inv);
        }
        *(u16x4*)&yrow[8 * g + 4 * hi]      = p0;
        *(u16x4*)&yrow[32 + 8 * g + 4 * hi] = p1;
    }
}

// ------------------------------- launcher ----------------------------------
extern "C" void kernel_launch(void* const* d_in, const int* in_sizes, int n_in,
                              void* d_out, int out_size, void* d_ws, size_t ws_size,
                              hipStream_t stream) {
    const float* x  = (const float*)d_in[0];
    const float* Wq = (const float*)d_in[1];
    const float* bq = (const float*)d_in[2];
    const float* Wk = (const float*)d_in[3];
    const float* bk = (const float*)d_in[4];
    const float* Wv = (const float*)d_in[5];
    const float* bv = (const float*)d_in[6];
    const float* Wo = (const float*)d_in[7];
    const float* bo = (const float*)d_in[8];
    float* out = (float*)d_out;

    const size_t XN = (size_t)MM * DD;   // 4,194,304
    const size_t WN = (size_t)DD * DD;   // 1,048,576

    u16* xb  = (u16*)d_ws;
    u16* Wb  = xb  + XN;          // Wq,Wk,Wv stacked: 3*WN
    u16* Wob = Wb  + 3 * WN;
    u16* QKV = Wob + WN;          // Q,K,V stacked: 3*XN
    u16* Yb  = QKV + 3 * XN;

    cvt_kernel<<<2048, 256, 0, stream>>>(x, xb, (int)(XN / 4));
    cvt4_kernel<<<dim3(256, 4), 256, 0, stream>>>(Wq, Wk, Wv, Wo,
            Wb, Wb + WN, Wb + 2 * WN, Wob, (int)(WN / 4));

    gemm_nt<0><<<dim3(32, 8, 3), 256, 0, stream>>>(xb, Wb, bq, bk, bv,
                                                   QKV, nullptr, MM, DD, DD);
    attn_kernel<<<dim3(16, BB * HH), 256, 0, stream>>>(QKV, QKV + XN,
                                                       QKV + 2 * XN, Yb);
    gemm_nt<1><<<dim3(32, 8, 1), 256, 0, stream>>>(Yb, Wob, bo, bo, bo,
                                                   nullptr, out, MM, DD, DD);
}